// Round 9
// baseline (195.558 us; speedup 1.0000x reference)
//
#include <hip/hip_runtime.h>
#include <math.h>

#define B_ 64
#define T_ 256
#define K_ 128

typedef const __attribute__((address_space(1))) void* gas1_t;
typedef __attribute__((address_space(3))) void* las3_t;
typedef float f32x4 __attribute__((ext_vector_type(4)));
typedef int   i32x8 __attribute__((ext_vector_type(8)));

// One wave per batch, ZERO barriers. mfma_scale_f32_16x16x128_f8f6f4 does the
// whole K=128 matvec in 8 independent MFMAs/step (A = E in e4m3, rows permuted
// by sigma(rt,m)=32(m>>2)+4rt+(m&3); B = v in e5m2 replicated over columns).
// Lane (g,ci) output rows {32g+4rt+r} == bytes (reg rt, byte r) of its next
// B-operand (k=32g+j): register-closed recurrence. Per-step renorm with the
// sum DEFERRED one step (shfl chain hides under next step's MFMA phase);
// out = sum_t log S_t exactly.
__global__ __launch_bounds__(64) void crf_fwd_kernel(
    const float* __restrict__ y,
    const float* __restrict__ mask,
    const float* __restrict__ trans,
    float* __restrict__ out)
{
    const int b    = blockIdx.x;
    const int lane = threadIdx.x;   // 0..63
    const int g    = lane >> 4;     // 0..3 : k-block [32g, 32g+32)
    const int ci   = lane & 15;     // A-row selector / replication index

    __shared__ __align__(16) float ybuf[2][32 * K_];   // 2 x 16 KB y chunks

    const float* yb = y + (size_t)b * (T_ * K_);
    auto stage = [&](int c, int buf) {
        const float* gp = yb + (size_t)c * (32 * K_);
        #pragma unroll
        for (int s = 0; s < 16; ++s)
            __builtin_amdgcn_global_load_lds(
                (gas1_t)(gp + s * 256 + lane * 4),
                (las3_t)(&ybuf[buf][s * 256]), 16, 0, 0);
    };
    stage(0, 0);

    // ---- sequence length (mask contiguous 1.0/0.0) ----
    float4 mv = *(const float4*)(mask + b * T_ + (lane << 2));
    float lc = (mv.x + mv.y) + (mv.z + mv.w);
    lc += __shfl_xor(lc, 1);
    lc += __shfl_xor(lc, 2);
    lc += __shfl_xor(lc, 4);
    lc += __shfl_xor(lc, 8);
    lc += __shfl_xor(lc, 16);
    lc += __shfl_xor(lc, 32);
    const int L = (int)lc;                 // in [128, 256]
    const int nch = (L + 31) >> 5;

    // ---- A-frags: E=exp(trans) in e4m3. Lane (g,ci), MFMA rt:
    //      A[m=ci][k=32g+j] = E[sigma(rt,ci)][32g+j],
    //      sigma(rt,ci) = 32*(ci>>2) + 4*rt + (ci&3). ----
    i32x8 A[8];
    #pragma unroll
    for (int rt = 0; rt < 8; ++rt) {
        const int R = 32 * (ci >> 2) + 4 * rt + (ci & 3);
        const float* tp = trans + R * K_ + 32 * g;
        i32x8 a;
        #pragma unroll
        for (int dw = 0; dw < 8; ++dw) {
            f32x4 v4 = *(const f32x4*)(tp + 4 * dw);
            int d = 0;
            d = __builtin_amdgcn_cvt_pk_fp8_f32(__expf(v4.x), __expf(v4.y), d, false);
            d = __builtin_amdgcn_cvt_pk_fp8_f32(__expf(v4.z), __expf(v4.w), d, true);
            a[dw] = d;
        }
        A[rt] = a;
    }

    // ---- v(0) = one-hot SOS (state 2): k=2 -> quad g=0, dword 0, byte 2.
    //      e5m2 1.0 = 0x3C ----
    i32x8 Bv = (i32x8){0, 0, 0, 0, 0, 0, 0, 0};
    if (g == 0) Bv[0] = 0x003C0000;

    float c_acc = 0.0f;
    float rDiv  = 1.0f;    // 1/S of previous step (deferred renorm)

    for (int c = 0; c < nch; ++c) {
        if (c + 1 < nch) {
            stage(c + 1, (c + 1) & 1);                          // prefetch next
            asm volatile("s_waitcnt vmcnt(16)" ::: "memory");   // chunk c done
        } else {
            asm volatile("s_waitcnt vmcnt(0)" ::: "memory");
        }
        float* bp = ybuf[c & 1];

        // pre-exp pass: 4096 floats / 64 lanes = 16 f32x4 per lane
        #pragma unroll
        for (int i = 0; i < 16; ++i) {
            f32x4 v4 = *(const f32x4*)(bp + i * 256 + (lane << 2));
            v4.x = __expf(v4.x); v4.y = __expf(v4.y);
            v4.z = __expf(v4.z); v4.w = __expf(v4.w);
            *(f32x4*)(bp + i * 256 + (lane << 2)) = v4;
        }

        const int rem = L - 32 * c;
        const int ns  = rem < 32 ? rem : 32;

        // preload ey for tt=0 : rows 32g+4rt..+3
        f32x4 eyc[8];
        #pragma unroll
        for (int rt = 0; rt < 8; ++rt)
            eyc[rt] = *(const f32x4*)(bp + 32 * g + 4 * rt);

        for (int tt = 0; tt < ns; ++tt) {
            // prefetch ey for tt+1 (no barrier -> latency hidden under MFMAs)
            const int tn = (tt + 1 < ns) ? tt + 1 : tt;
            f32x4 eyn[8];
            #pragma unroll
            for (int rt = 0; rt < 8; ++rt)
                eyn[rt] = *(const f32x4*)(bp + tn * K_ + 32 * g + 4 * rt);

            // 8 independent full-K MFMAs; w = u .* ey / S_prev; pack e5m2
            f32x4 sv = {0.f, 0.f, 0.f, 0.f};
            i32x8 Bn;
            #pragma unroll
            for (int rt = 0; rt < 8; ++rt) {
                f32x4 u = __builtin_amdgcn_mfma_scale_f32_16x16x128_f8f6f4(
                    A[rt], Bv, (f32x4){0.f, 0.f, 0.f, 0.f},
                    0 /*A fmt = fp8 e4m3*/, 1 /*B fmt = bf8 e5m2*/,
                    0, 127 /*scaleA = 1.0*/, 0, 127 /*scaleB = 1.0*/);
                f32x4 w = u * eyc[rt] * rDiv;
                sv += w;
                int d = 0;
                d = __builtin_amdgcn_cvt_pk_bf8_f32(w.x, w.y, d, false);
                d = __builtin_amdgcn_cvt_pk_bf8_f32(w.z, w.w, d, true);
                Bn[rt] = d;
            }

            // deferred renorm: S's shfl chain overlaps NEXT step's MFMA phase
            float S = (sv.x + sv.y) + (sv.z + sv.w);   // lane's 32 disjoint rows
            S += __shfl_xor(S, 16);                    // combine 4 quads
            S += __shfl_xor(S, 32);
            c_acc += __logf(S);
            rDiv = __builtin_amdgcn_rcpf(S);

            Bv = Bn;
            #pragma unroll
            for (int rt = 0; rt < 8; ++rt) eyc[rt] = eyn[rt];
        }
    }

    // out = sum_t log S_t
    if (lane == 0) out[b] = c_acc;
}

extern "C" void kernel_launch(void* const* d_in, const int* in_sizes, int n_in,
                              void* d_out, int out_size, void* d_ws, size_t ws_size,
                              hipStream_t stream) {
    const float* y     = (const float*)d_in[0];   // (B, T, K) fp32
    const float* mask  = (const float*)d_in[1];   // (B, T)    fp32 0/1
    const float* trans = (const float*)d_in[2];   // (K, K)    fp32
    float* out = (float*)d_out;                    // (B,)      fp32
    crf_fwd_kernel<<<B_, 64, 0, stream>>>(y, mask, trans, out);
}